// Round 2
// baseline (38.846 us; speedup 1.0000x reference)
//
#include <hip/hip_runtime.h>

#define TPB 256
typedef float v4f __attribute__((ext_vector_type(4)));

#define NTL(p)     __builtin_nontemporal_load(p)
#define NTS(v, p)  __builtin_nontemporal_store((v), (p))

// One Euler-Maruyama step with closed-form polar (Rodrigues) retraction.
// x <- x * (I + c1*S + c2*S^2), S = hs*(x^T e - e^T x) skew, axial (A,Bv,Cv).
__device__ __forceinline__ void so3_step(float x[9], const float e[9], float hs) {
    float wa = 0.f, wb = 0.f, wc = 0.f;
    #pragma unroll
    for (int k = 0; k < 3; ++k) {
        const float xk0 = x[k*3+0], xk1 = x[k*3+1], xk2 = x[k*3+2];
        const float ek0 = e[k*3+0], ek1 = e[k*3+1], ek2 = e[k*3+2];
        wa += xk2*ek1 - xk1*ek2;
        wb += xk0*ek2 - xk2*ek0;
        wc += xk1*ek0 - xk0*ek1;
    }
    const float A  = hs * wa;
    const float Bv = hs * wb;
    const float Cv = hs * wc;

    const float th2 = A*A + Bv*Bv + Cv*Cv;
    const float c1  = rsqrtf(1.0f + th2);
    const float c2  = c1*c1 / (1.0f + c1);   // (1 - c1)/th2, stable at th2 -> 0

    const float q00 = 1.0f - c2*(Bv*Bv + Cv*Cv);
    const float q11 = 1.0f - c2*(A*A  + Cv*Cv);
    const float q22 = 1.0f - c2*(A*A  + Bv*Bv);
    const float q01 = c2*A*Bv  - c1*Cv;
    const float q10 = c2*A*Bv  + c1*Cv;
    const float q02 = c2*A*Cv  + c1*Bv;
    const float q20 = c2*A*Cv  - c1*Bv;
    const float q12 = c2*Bv*Cv - c1*A;
    const float q21 = c2*Bv*Cv + c1*A;

    #pragma unroll
    for (int r = 0; r < 3; ++r) {
        const float a0 = x[r*3+0], a1 = x[r*3+1], a2 = x[r*3+2];
        x[r*3+0] = a0*q00 + a1*q10 + a2*q20;
        x[r*3+1] = a0*q01 + a1*q11 + a2*q21;
        x[r*3+2] = a0*q02 + a1*q12 + a2*q22;
    }
}

__global__ __launch_bounds__(TPB) void brownian_so3_kernel(
    const float* __restrict__ x0,
    const float* __restrict__ t,
    const float* __restrict__ noise,
    float* __restrict__ out,
    int B, int steps)
{
    __shared__ float lds[2][TPB * 9];

    const int tid   = threadIdx.x;
    const long base = (long)blockIdx.x * TPB * 9;   // float offset of block tile
    const int  b    = blockIdx.x * TPB + tid;

    const float tv = t[b];   // issue early, independent

    // ---- Stage x0 tile (coalesced float4) ----
    {
        const v4f* src = (const v4f*)(x0 + base);
        v4f* dst = (v4f*)lds[0];
        dst[tid]       = NTL(src + tid);
        dst[tid + TPB] = NTL(src + tid + TPB);
        if (tid < 64) dst[tid + 2*TPB] = NTL(src + tid + 2*TPB);
    }
    __syncthreads();
    float x[9];
    #pragma unroll
    for (int j = 0; j < 9; ++j) x[j] = lds[0][tid*9 + j];
    __syncthreads();   // lds[0] gets overwritten by step-0 noise below

    const float hs = 0.5f * sqrtf(tv / (float)steps);

    // ---- Depth-2 prefetch: register set a = even tiles, b = odd tiles ----
    v4f a0, a1, a2, b0, b1, b2;
    a2 = (v4f)0.f; b2 = (v4f)0.f;
    {
        const v4f* s0 = (const v4f*)(noise + base);
        a0 = NTL(s0 + tid);
        a1 = NTL(s0 + tid + TPB);
        if (tid < 64) a2 = NTL(s0 + tid + 2*TPB);
    }
    if (1 < steps) {
        const v4f* s1 = (const v4f*)(noise + (long)B*9 + base);
        b0 = NTL(s1 + tid);
        b1 = NTL(s1 + tid + TPB);
        if (tid < 64) b2 = NTL(s1 + tid + 2*TPB);
    }

    float e[9];
    int s = 0;
    for (; s + 1 < steps; s += 2) {
        // ---- even step: consume a (tile s), refill a with tile s+2 ----
        {
            v4f* dst = (v4f*)lds[0];
            dst[tid] = a0; dst[tid + TPB] = a1;
            if (tid < 64) dst[tid + 2*TPB] = a2;
        }
        if (s + 2 < steps) {
            const v4f* src = (const v4f*)(noise + (long)(s+2) * B * 9 + base);
            a0 = NTL(src + tid);
            a1 = NTL(src + tid + TPB);
            if (tid < 64) a2 = NTL(src + tid + 2*TPB);
        }
        __syncthreads();
        #pragma unroll
        for (int j = 0; j < 9; ++j) e[j] = lds[0][tid*9 + j];
        so3_step(x, e, hs);

        // ---- odd step: consume b (tile s+1), refill b with tile s+3 ----
        {
            v4f* dst = (v4f*)lds[1];
            dst[tid] = b0; dst[tid + TPB] = b1;
            if (tid < 64) dst[tid + 2*TPB] = b2;
        }
        if (s + 3 < steps) {
            const v4f* src = (const v4f*)(noise + (long)(s+3) * B * 9 + base);
            b0 = NTL(src + tid);
            b1 = NTL(src + tid + TPB);
            if (tid < 64) b2 = NTL(src + tid + 2*TPB);
        }
        __syncthreads();
        #pragma unroll
        for (int j = 0; j < 9; ++j) e[j] = lds[1][tid*9 + j];
        so3_step(x, e, hs);
    }
    if (s < steps) {   // odd trailing step (not hit for steps=20; kept for safety)
        {
            v4f* dst = (v4f*)lds[0];
            dst[tid] = a0; dst[tid + TPB] = a1;
            if (tid < 64) dst[tid + 2*TPB] = a2;
        }
        __syncthreads();
        #pragma unroll
        for (int j = 0; j < 9; ++j) e[j] = lds[0][tid*9 + j];
        so3_step(x, e, hs);
    }

    // ---- Store result via LDS transpose (coalesced float4 NT stores) ----
    __syncthreads();   // all reads of lds done before overwrite
    float* obuf = lds[0];
    #pragma unroll
    for (int j = 0; j < 9; ++j) obuf[tid*9 + j] = x[j];
    __syncthreads();
    {
        v4f* dst = (v4f*)(out + base);
        const v4f* src = (const v4f*)obuf;
        NTS(src[tid],       dst + tid);
        NTS(src[tid + TPB], dst + tid + TPB);
        if (tid < 64) NTS(src[tid + 2*TPB], dst + tid + 2*TPB);
    }
}

extern "C" void kernel_launch(void* const* d_in, const int* in_sizes, int n_in,
                              void* d_out, int out_size, void* d_ws, size_t ws_size,
                              hipStream_t stream) {
    const float* x0    = (const float*)d_in[0];
    const float* t     = (const float*)d_in[1];
    const float* noise = (const float*)d_in[2];
    float* out = (float*)d_out;

    const int B     = in_sizes[0] / 9;
    const int steps = in_sizes[2] / in_sizes[0];

    const int grid = B / TPB;   // 262144 / 256 = 1024 blocks
    brownian_so3_kernel<<<grid, TPB, 0, stream>>>(x0, t, noise, out, B, steps);
}

// Round 3
// 37.688 us; speedup vs baseline: 1.0307x; 1.0307x over previous
//
#include <hip/hip_runtime.h>

#define TPB 256
// 4-byte-aligned float4: sample bases are 36B-aligned, so 16B loads sit at
// align-4 addresses. gfx9+ global loads support dword alignment in HW.
typedef float v4fa __attribute__((ext_vector_type(4), aligned(4)));

#define NTS(v, p)  __builtin_nontemporal_store((v), (p))

// One Euler-Maruyama step with closed-form polar (Rodrigues) retraction.
// x <- x * (I + c1*S + c2*S^2), S = hs*(x^T e - e^T x) skew, axial (A,Bv,Cv).
__device__ __forceinline__ void so3_step(float x[9], const float e[9], float hs) {
    float wa = 0.f, wb = 0.f, wc = 0.f;
    #pragma unroll
    for (int k = 0; k < 3; ++k) {
        const float xk0 = x[k*3+0], xk1 = x[k*3+1], xk2 = x[k*3+2];
        const float ek0 = e[k*3+0], ek1 = e[k*3+1], ek2 = e[k*3+2];
        wa += xk2*ek1 - xk1*ek2;
        wb += xk0*ek2 - xk2*ek0;
        wc += xk1*ek0 - xk0*ek1;
    }
    const float A  = hs * wa;
    const float Bv = hs * wb;
    const float Cv = hs * wc;

    const float th2 = A*A + Bv*Bv + Cv*Cv;
    const float c1  = rsqrtf(1.0f + th2);
    const float c2  = c1*c1 / (1.0f + c1);   // (1 - c1)/th2, stable at th2 -> 0

    const float q00 = 1.0f - c2*(Bv*Bv + Cv*Cv);
    const float q11 = 1.0f - c2*(A*A  + Cv*Cv);
    const float q22 = 1.0f - c2*(A*A  + Bv*Bv);
    const float q01 = c2*A*Bv  - c1*Cv;
    const float q10 = c2*A*Bv  + c1*Cv;
    const float q02 = c2*A*Cv  + c1*Bv;
    const float q20 = c2*A*Cv  - c1*Bv;
    const float q12 = c2*Bv*Cv - c1*A;
    const float q21 = c2*Bv*Cv + c1*A;

    #pragma unroll
    for (int r = 0; r < 3; ++r) {
        const float a0 = x[r*3+0], a1 = x[r*3+1], a2 = x[r*3+2];
        x[r*3+0] = a0*q00 + a1*q10 + a2*q20;
        x[r*3+1] = a0*q01 + a1*q11 + a2*q21;
        x[r*3+2] = a0*q02 + a1*q12 + a2*q22;
    }
}

__device__ __forceinline__ void load9(const float* __restrict__ p, float e[9]) {
    v4fa lo = *(const v4fa*)(p);
    v4fa hi = *(const v4fa*)(p + 4);
    e[0] = lo.x; e[1] = lo.y; e[2] = lo.z; e[3] = lo.w;
    e[4] = hi.x; e[5] = hi.y; e[6] = hi.z; e[7] = hi.w;
    e[8] = p[8];
}

__global__ __launch_bounds__(TPB) void brownian_so3_kernel(
    const float* __restrict__ x0,
    const float* __restrict__ t,
    const float* __restrict__ noise,
    float* __restrict__ out,
    int B, int steps)
{
    const int b = blockIdx.x * TPB + threadIdx.x;   // one sample per thread

    const float tv = t[b];

    float x[9];
    load9(x0 + (long)b * 9, x);

    const long stride = (long)B * 9;
    const float* np = noise + (long)b * 9;

    // Register double-buffer: cur = tile s, nxt = tile s+1 (in flight).
    float cur[9], nxt[9];
    load9(np, cur);
    if (steps > 1) load9(np + stride, nxt);

    const float hs = 0.5f * sqrtf(tv / (float)steps);

    for (int s = 0; s < steps; ++s) {
        // Kick off load for s+2 before computing on cur — keeps 2 tiles in flight.
        float e[9];
        #pragma unroll
        for (int j = 0; j < 9; ++j) e[j] = cur[j];
        #pragma unroll
        for (int j = 0; j < 9; ++j) cur[j] = nxt[j];
        if (s + 2 < steps) load9(np + (long)(s + 2) * stride, cur);
        // note: after the swap, `cur` now receives tile s+2 while `e` holds tile s
        // and the old nxt (tile s+1) was copied into... (see below)
        so3_step(x, e, hs);
        #pragma unroll
        for (int j = 0; j < 9; ++j) { float tmp = cur[j]; cur[j] = nxt[j]; nxt[j] = tmp; }
        // After this swap: cur = tile s+1 (ready for next iter), nxt = tile s+2 (in flight).
    }

    // Direct per-lane NT store of the 9 result floats.
    float* op = out + (long)b * 9;
    v4fa lo, hi;
    lo.x = x[0]; lo.y = x[1]; lo.z = x[2]; lo.w = x[3];
    hi.x = x[4]; hi.y = x[5]; hi.z = x[6]; hi.w = x[7];
    NTS(lo, (v4fa*)op);
    NTS(hi, (v4fa*)(op + 4));
    NTS(x[8], op + 8);
}

extern "C" void kernel_launch(void* const* d_in, const int* in_sizes, int n_in,
                              void* d_out, int out_size, void* d_ws, size_t ws_size,
                              hipStream_t stream) {
    const float* x0    = (const float*)d_in[0];
    const float* t     = (const float*)d_in[1];
    const float* noise = (const float*)d_in[2];
    float* out = (float*)d_out;

    const int B     = in_sizes[0] / 9;
    const int steps = in_sizes[2] / in_sizes[0];

    const int grid = B / TPB;   // 262144 / 256 = 1024 blocks
    brownian_so3_kernel<<<grid, TPB, 0, stream>>>(x0, t, noise, out, B, steps);
}